// Round 13
// baseline (117.994 us; speedup 1.0000x reference)
//
#include <hip/hip_runtime.h>

// Depth rasterization, MI355X — round 13.
// R12 post-mortem: top-5 dispatches are the HARNESS's 268MB d_ws poison
// (39.5us @ 84% HBM peak) — the "fixed ~50us overhead" is mostly that.
// Raster inferred ~35-40us: binning didn't pay because each wave pulls 32
// scattered 64B records through the 16KB scalar K$ with zero reuse -> all
// misses, in-order scalar pipe exposes ~300-500cyc each.
// Fix: bin_kernel PACKS surviving records densely per bin; raster wave
// stages its 2KB piece with TWO coalesced float4 VMEM loads into a private
// LDS region, face loop reads uniform-address ds_read_b128 broadcasts
// (128 x 12cyc = 1.5Kcyc, hidden under ~6Kcyc VALU).  No s_loads, no
// indices, no __syncthreads (waves own disjoint LDS halves).
// Math bit-identical to numpy: contract off, reference op order, s=+-1
// folds exact, cross-mult min, one IEEE divide per pixel.

#pragma clang fp contract(off)

#define H_OUT 128
#define W_OUT 128
#define NV 778
#define NF 1538
#define NB 4
#define NFP 1600                   // padded faces per batch (pads always-miss)
#define CAP 2048                   // record capacity per bin (max bin ~1100)
#define BG100 0x42C80000u          // 100.0f bits (uint order == float order >0)

// data/packed record (16 floats / 64B):
// [0]s*dx12 [1]s*dy12 [2]s*dx02 [3]s*dy02 [4]s*dx01 [5]s*dy01
// [6]x0 [7]y0 [8]x1 [9]y1 [10]x2 [11]y2  [12]z0 [13]z1 [14]z2 [15]s*area
// bbox record (4 floats): xmin, xmax, ymin, ymax  (pad: inverted -> unbinned)

__global__ __launch_bounds__(256) void prep_kernel(
    const float* __restrict__ verts,   // [NB][NV][3]
    const int* __restrict__ faces,     // [NF][3]
    float* __restrict__ bbox,          // [NB*NFP][4]
    float* __restrict__ data,          // [NB*NFP][16]
    unsigned int* __restrict__ outu)   // [NB*16384]
{
    int t = blockIdx.x * 256 + threadIdx.x;   // grid 256 blocks = 65536
    outu[t] = BG100;                           // init z-buffer to 100.0f
    if (t >= NB * NFP) return;
    int b = t / NFP;
    int f = t - b * NFP;
    float* bb = bbox + (size_t)t * 4;
    float* o  = data + (size_t)t * 16;
    if (f >= NF) {                             // pad face: never binned; as a
        bb[0] = 1e30f; bb[1] = -1e30f; bb[2] = 1e30f; bb[3] = -1e30f;
        o[0] = 0.0f; o[1] = 1.0f;              // pad record: e0 < 0 -> miss
        o[2] = 0.0f; o[3] = 0.0f; o[4] = 0.0f; o[5] = 0.0f;
        o[6] = 0.0f; o[7] = 0.0f; o[8] = -1e30f; o[9] = 0.0f;
        o[10] = 0.0f; o[11] = 0.0f; o[12] = 0.0f; o[13] = 0.0f; o[14] = 0.0f;
        o[15] = 1.0f;                          // harmless area
        return;
    }
    int i0 = faces[f * 3 + 0];
    int i1 = faces[f * 3 + 1];
    int i2 = faces[f * 3 + 2];
    const float* vb = verts + (size_t)b * NV * 3;
    float x0 = vb[i0 * 3 + 0], y0 = vb[i0 * 3 + 1], z0 = vb[i0 * 3 + 2];
    float x1 = vb[i1 * 3 + 0], y1 = vb[i1 * 3 + 1], z1 = vb[i1 * 3 + 2];
    float x2 = vb[i2 * 3 + 0], y2 = vb[i2 * 3 + 1], z2 = vb[i2 * 3 + 2];

    // Reference deltas (single RN subtracts) and area (reference op order).
    float dx12 = x2 - x1, dy12 = y2 - y1;
    float dx02 = x0 - x2, dy02 = y0 - y2;
    float dx01 = x1 - x0, dy01 = y1 - y0;
    float y20 = y2 - y0, x20 = x2 - x0;
    float area = dx01 * y20 - dy01 * x20;

    float s = 0.0f;
    if (fabsf(area) > 1e-12f) s = (area > 0.0f) ? 1.0f : -1.0f;

    float xmin = fminf(fminf(x0, x1), x2), xmax = fmaxf(fmaxf(x0, x1), x2);
    float ymin = fminf(fminf(y0, y1), y2), ymax = fmaxf(fmaxf(y0, y1), y2);
    if (s == 0.0f) { xmin = 1e30f; xmax = -1e30f; }  // degenerate -> unbinned

    bb[0] = xmin; bb[1] = xmax; bb[2] = ymin; bb[3] = ymax;

    o[0] = s * dx12; o[1] = s * dy12;        // exact sign folds (s = +-1)
    o[2] = s * dx02; o[3] = s * dy02;
    o[4] = s * dx01; o[5] = s * dy01;
    o[6] = x0;  o[7] = y0;  o[8] = x1;  o[9] = y1;  o[10] = x2; o[11] = y2;
    o[12] = z0; o[13] = z1; o[14] = z2; o[15] = s * area;   // = |area| > 0
}

__global__ __launch_bounds__(64) void bin_kernel(
    const float* __restrict__ bbox,    // [NB*NFP][4]
    const float* __restrict__ data,    // [NB*NFP][16]
    float* __restrict__ packed,        // [256][CAP][16] packed records
    unsigned int* __restrict__ count)  // [256] padded counts (x32)
{
    int bin = blockIdx.x;              // 256 = batch(4) x tile(64)
    int b = bin >> 6, tile = bin & 63;
    int tx = tile & 7, ty = tile >> 3;
    int lane = threadIdx.x;            // one wave
    int gb = b * NFP;

    float px_lo = 80.0f * (float)tx + 2.5f, px_hi = px_lo + 75.0f;
    float py_lo = 80.0f * (float)ty + 2.5f, py_hi = py_lo + 75.0f;

    float* pk = packed + (size_t)bin * CAP * 16;
    unsigned int base = 0;
    for (int c = 0; c < NFP / 64; ++c) {
        int f = c * 64 + lane;
        float4 bb = *(const float4*)&bbox[(size_t)(gb + f) * 4];
        bool ov = !(bb.x > px_hi || bb.y < px_lo ||
                    bb.z > py_hi || bb.w < py_lo);
        unsigned long long m = __ballot(ov);
        if (ov) {                               // copy own 64B record (dense,
            int pre = __popcll(m & ((1ull << lane) - 1ull));  // order-kept)
            const float4* src = (const float4*)(data + (size_t)(gb + f) * 16);
            float4 r0 = src[0], r1 = src[1], r2 = src[2], r3 = src[3];
            float4* dst = (float4*)(pk + (size_t)(base + pre) * 16);
            dst[0] = r0; dst[1] = r1; dst[2] = r2; dst[3] = r3;
        }
        base += (unsigned int)__popcll(m);
    }
    // Pad to a multiple of 32 with the always-miss pad record (NFP-1).
    unsigned int padN = (32u - (base & 31u)) & 31u;
    if ((unsigned int)lane < padN) {
        const float4* src = (const float4*)(data + (size_t)(gb + NFP - 1) * 16);
        float4 r0 = src[0], r1 = src[1], r2 = src[2], r3 = src[3];
        float4* dst = (float4*)(pk + (size_t)(base + lane) * 16);
        dst[0] = r0; dst[1] = r1; dst[2] = r2; dst[3] = r3;
    }
    if (lane == 0) count[bin] = base + padN;
}

// One pixel-row update (named accumulators; exact reference op order).
#define PIX(PY, NBv, ABv)                                                   \
    {                                                                       \
        float e0 = A.x * ((PY) - C.y) - hx0;                                \
        float e1 = A.z * ((PY) - C.w) - hx1;                                \
        float e2 = B.x * ((PY) - B.w) - hx2;                                \
        bool ins = (e0 >= 0.0f) & (e1 >= 0.0f) & (e2 >= 0.0f);              \
        float n = ((e0 * D.x) + (e1 * D.y)) + (e2 * D.z);                   \
        bool tk = ins & (n * (ABv) < (NBv) * D.w);                          \
        NBv = tk ? n : (NBv);  ABv = tk ? D.w : (ABv);                      \
    }

__global__ __launch_bounds__(128) void raster_kernel(
    const float* __restrict__ packed,        // [256][CAP][16]
    const unsigned int* __restrict__ count,  // [256]
    unsigned int* __restrict__ outu)         // [NB*16384], init 100.0f bits
{
    __shared__ float lds[2][32 * 16];  // one 2KB piece per wave (disjoint)

    int blk = blockIdx.x;              // 8192 = piecepair(32) x bin(256)
    int bin = blk & 255;               // piece-major: active blocks first
    int pp  = blk >> 8;
    int tid = threadIdx.x;             // 128 thr = 2 waves = 2 pieces
    int w = __builtin_amdgcn_readfirstlane(tid >> 6);
    int piece = pp * 2 + w;

    unsigned int cnt = count[bin];     // wave-uniform s_load
    if ((unsigned int)(piece * 32) >= cnt) return;   // empty piece (per wave)

    int lane = tid & 63;
    // Stage this wave's 32 records (2KB) with two coalesced float4 loads.
    const float4* src =
        (const float4*)(packed + ((size_t)bin * CAP + (size_t)piece * 32) * 16);
    float4 s0 = src[lane], s1 = src[lane + 64];
    float* L = lds[w];
    ((float4*)L)[lane]      = s0;
    ((float4*)L)[lane + 64] = s1;
    // Same-wave ds_write -> ds_read on the same array: compiler inserts the
    // lgkmcnt wait.  No cross-wave sharing -> no __syncthreads needed.

    int b = bin >> 6, tile = bin & 63;
    int tx = tile & 7, ty = tile >> 3;
    int col = lane & 15;
    int rg  = lane >> 4;               // lane rows: rg + 4k, k = 0..3
    int j = tx * 16 + col;
    int i0r = ty * 16 + rg;
    float px  = 5.0f * (float)j + 2.5f;
    float py0 = 5.0f * (float)i0r + 2.5f;    // +20k exact (multiples of 2.5)
    float py1 = py0 + 20.0f, py2 = py0 + 40.0f, py3 = py0 + 60.0f;

    float nb0 = 1e10f, ab0 = 1.0f;     // named accumulators (registers)
    float nb1 = 1e10f, ab1 = 1.0f;
    float nb2 = 1e10f, ab2 = 1.0f;
    float nb3 = 1e10f, ab3 = 1.0f;

    // 32 faces, uniform-address LDS broadcasts (no bank conflicts), 4px each.
    #pragma unroll 4
    for (int f = 0; f < 32; ++f) {
        const float4* p = (const float4*)&L[f * 16];
        float4 A = p[0], B = p[1], C = p[2], D = p[3];
        float hx0 = A.y * (px - C.x);  // k-invariant hoists (exact reuse)
        float hx1 = A.w * (px - C.z);
        float hx2 = B.y * (px - B.z);
        PIX(py0, nb0, ab0)
        PIX(py1, nb1, ab1)
        PIX(py2, nb2, ab2)
        PIX(py3, nb3, ab3)
    }

    // Epilogue: one IEEE divide + atomic per pixel (4 per lane).
    unsigned int* slot0 = &outu[(size_t)b * (H_OUT * W_OUT) + i0r * W_OUT + j];
    {
        float z = nb0 / ab0; z += 0.0f;
        if (z < 1e9f) atomicMin(slot0, __float_as_uint(fminf(z, 100.0f)));
    }
    {
        float z = nb1 / ab1; z += 0.0f;
        if (z < 1e9f) atomicMin(slot0 + 4 * W_OUT, __float_as_uint(fminf(z, 100.0f)));
    }
    {
        float z = nb2 / ab2; z += 0.0f;
        if (z < 1e9f) atomicMin(slot0 + 8 * W_OUT, __float_as_uint(fminf(z, 100.0f)));
    }
    {
        float z = nb3 / ab3; z += 0.0f;
        if (z < 1e9f) atomicMin(slot0 + 12 * W_OUT, __float_as_uint(fminf(z, 100.0f)));
    }
}

extern "C" void kernel_launch(void* const* d_in, const int* in_sizes, int n_in,
                              void* d_out, int out_size, void* d_ws, size_t ws_size,
                              hipStream_t stream) {
    const float* verts = (const float*)d_in[0];   // [4][778][3] f32
    const int*   faces = (const int*)d_in[1];     // [1538][3] i32
    float* out = (float*)d_out;                   // [4][128][128] f32
    float* bbox = (float*)d_ws;                          // 102 KB
    float* data = bbox + (size_t)NB * NFP * 4;           // 410 KB
    float* packed = data + (size_t)NB * NFP * 16;        // 256*2048*64B = 33.5 MB
    unsigned int* count =
        (unsigned int*)(packed + (size_t)256 * CAP * 16);  // 1 KB

    prep_kernel<<<256, 256, 0, stream>>>(verts, faces, bbox, data,
                                         (unsigned int*)out);
    bin_kernel<<<256, 64, 0, stream>>>(bbox, data, packed, count);
    raster_kernel<<<32 * 256, 128, 0, stream>>>(
        packed, count, (unsigned int*)out);
}